// Round 3
// baseline (1160.794 us; speedup 1.0000x reference)
//
#include <hip/hip_runtime.h>

// SNN fused forward: 3-layer LIF, T=100, B=32768, dims 128->256->256->8.
// Block = 16 batch rows, 512 threads (8 waves), full 100-step sim in one kernel.
// Layer-1 GEMM: mfma_f32_16x16x32_f16 with exact fp16 hi/lo weight split held
// entirely in VGPRs (spikes are exact in fp16; fp32 accumulate => fp32-class
// numerics). Spikes double-buffered in LDS; writes are ballot-packed so each
// lane issues ONE ds_write_b128 per step (vs 8 scattered b16). Output layer
// folded into closed-form Z = sum_t c_t * s1_t; out = Z @ W2 via LDS atomics.

typedef _Float16 f16;
typedef _Float16 f16x8 __attribute__((ext_vector_type(8)));
typedef float    f32x4 __attribute__((ext_vector_type(4)));
typedef int      i32x4 __attribute__((ext_vector_type(4)));
typedef unsigned int u32;
typedef unsigned long long u64;

#define SIM_T   100
#define MROWS   16
#define BLOCKSZ 512
#define RECIP2048 4.8828125e-4f

#define MFMA16(a, b, c) __builtin_amdgcn_mfma_f32_16x16x32_f16((a), (b), (c), 0, 0, 0)

__global__ __launch_bounds__(BLOCKSZ, 2)
void snn_fused(const float* __restrict__ input,
               const float* __restrict__ W0,
               const float* __restrict__ W1,
               const float* __restrict__ W2,
               float* __restrict__ out)
{
    // Spike layout: addr(r, k) = ((k>>3)*16 + ((r + (k>>3)) & 15))*16 + (k&7)*2
    // -> A-frag ds_read_b128 is 16 consecutive bytes; chunk spans cover all 32
    //    banks 2-way (free) for both reads and the packed b128 writes.
    __shared__ __align__(16) char spk[2][8192];
    __shared__ float h2acc[MROWS * 8];
    __shared__ float ctab[SIM_T];

    const int tid  = threadIdx.x;
    const int wv   = tid >> 6;      // wave: owns layer-1 cols [32wv, 32wv+32)
    const int ln   = tid & 63;
    const int mrow = ln & 15;       // MFMA 16-row / B-col index; also spike-write row
    const int g    = ln >> 4;       // MFMA k-group; also spike-write col-oct
    const int row0 = blockIdx.x * MROWS;
    const int n0   = wv * 32;

    if (tid < MROWS * 8) h2acc[tid] = 0.0f;
    if (tid < SIM_T) {
        // c_tau = (0.9^n - 0.85^n)/0.05, n = 99 - tau
        const float n = (float)(SIM_T - 1 - tid);
        ctab[tid] = 20.0f * (exp2f(n * -0.15200309344504997f)
                           - exp2f(n * -0.23446525363702297f));
    }

    // ---- stage input tile into LDS (overlays spk[0]) ----
    float* instage = (float*)&spk[0][0];
    #pragma unroll
    for (int i = 0; i < 4; ++i)   // 4*512 = 2048 = 16*128
        instage[i * BLOCKSZ + tid] = input[(size_t)row0 * 128 + i * BLOCKSZ + tid];
    __syncthreads();

    // ---- input A-fragments, exact fp16 hi/lo split ----
    f16x8 xh[4], xl[4];
    #pragma unroll
    for (int kc = 0; kc < 4; ++kc) {
        const float* p = instage + mrow * 128 + kc * 32 + g * 8;
        f16x8 vh, vl;
        #pragma unroll
        for (int e = 0; e < 8; ++e) {
            const float x = p[e];
            const f16 h = (f16)x;
            vh[e] = h;
            vl[e] = (f16)((x - (float)h) * 2048.0f);
        }
        xh[kc] = vh; xl[kc] = vl;
    }

    // ---- H0 = input @ W0 via MFMA: hi*hi + (hi*lo + lo*hi)/2048 ----
    f32x4 h0a[2], h0b[2];
    #pragma unroll
    for (int nt = 0; nt < 2; ++nt) { h0a[nt] = (f32x4){0,0,0,0}; h0b[nt] = (f32x4){0,0,0,0}; }
    #pragma unroll
    for (int nt = 0; nt < 2; ++nt) {
        const int col = n0 + nt * 16 + mrow;
        #pragma unroll
        for (int kc = 0; kc < 4; ++kc) {
            const int kb = kc * 32 + g * 8;
            f16x8 bh, bl;
            #pragma unroll
            for (int e = 0; e < 8; ++e) {
                const float w = W0[(kb + e) * 256 + col];
                const f16 h = (f16)w;
                bh[e] = h;
                bl[e] = (f16)((w - (float)h) * 2048.0f);
            }
            h0a[nt] = MFMA16(xh[kc], bh, h0a[nt]);
            h0b[nt] = MFMA16(xh[kc], bl, h0b[nt]);
            h0b[nt] = MFMA16(xl[kc], bh, h0b[nt]);
        }
    }

    // Layer-0 state in MFMA C-layout: elem i = nt*4+q ->
    // (batch row r = g*4+q, layer-0 neuron j = n0 + nt*16 + mrow)
    float H0c[8], syn0[8], mem0[8];
    #pragma unroll
    for (int nt = 0; nt < 2; ++nt)
        #pragma unroll
        for (int q = 0; q < 4; ++q) {
            H0c[nt * 4 + q]  = h0a[nt][q] + RECIP2048 * h0b[nt][q];
            syn0[nt * 4 + q] = 0.0f;
            mem0[nt * 4 + q] = 0.0f;
        }

    // ---- W1 -> VGPRs, exact fp16 hi/lo split (128 VGPRs) ----
    f16x8 whi[2][8], wlo[2][8];
    #pragma unroll
    for (int nt = 0; nt < 2; ++nt) {
        const int col = n0 + nt * 16 + mrow;
        #pragma unroll
        for (int kc = 0; kc < 8; ++kc) {
            const int kb = kc * 32 + g * 8;
            f16x8 vh, vl;
            #pragma unroll
            for (int e = 0; e < 8; ++e) {
                const float w = W1[(kb + e) * 256 + col];
                const f16 h = (f16)w;
                vh[e] = h;
                vl[e] = (f16)((w - (float)h) * 2048.0f);
            }
            whi[nt][kc] = vh; wlo[nt][kc] = vl;
        }
    }

    // ---- precomputed LDS addresses ----
    // Ballot-packed spike write: lane (mrow, g) writes row mrow,
    // cols n0 + g*8 .. +7 (k-contiguous) => one b128. slot = wv*4 + g.
    int wba;
    {
        const int slot = wv * 4 + g;
        wba = (slot * 16 + ((mrow + slot) & 15)) * 16;
    }
    const int shamt = ((mrow >> 2) & 1) * 16 + (g & 1) * 8;   // bit offset in u32 half
    int ra[8];   // A-frag reads: (r = mrow, slot = kc*4+g)
    #pragma unroll
    for (int kc = 0; kc < 8; ++kc) {
        const int slot = kc * 4 + g;
        ra[kc] = (slot * 16 + ((mrow + slot) & 15)) * 16;
    }

    float syn1[8], mem1[8], Zc[8];
    #pragma unroll
    for (int i = 0; i < 8; ++i) { syn1[i] = 0.0f; mem1[i] = 0.0f; Zc[i] = 0.0f; }

    __syncthreads();   // instage reads done; spk[0] becomes spike buffer

    char* spkbase = &spk[0][0];
    int bufoff = 0;

    #pragma unroll 1
    for (int t = 0; t < SIM_T; ++t) {
        // ---- layer 0: ballot spikes from OLD mem0; state update (old syn0) ----
        u64 bal[8];
        #pragma unroll
        for (int i = 0; i < 8; ++i) {           // fully unrolled -> static indices
            const float m = mem0[i], s = syn0[i];
            const bool fire = m > 1.0f;
            bal[i] = __ballot(fire);
            const float f = fire ? 1.0f : 0.0f;
            mem0[i] = fmaf(0.85f, m, s) - f;
            syn0[i] = fmaf(0.9f, s, H0c[i]);
        }
        // bal[nt*4+q] bit (g'*16+m') = spike(row g'*4+q, col n0+nt*16+m').
        // This lane needs row mrow, cols n0+g*8..+7:
        //   word i = (g>>1)*4 + (mrow&3), bits [(mrow>>2)*16 + (g&1)*8 .. +8)
        {
            const int rq = mrow & 3;
            const u64 s01 = (rq & 1) ? bal[1] : bal[0];
            const u64 s23 = (rq & 1) ? bal[3] : bal[2];
            const u64 sA  = (rq & 2) ? s23 : s01;      // nt = 0
            const u64 s45 = (rq & 1) ? bal[5] : bal[4];
            const u64 s67 = (rq & 1) ? bal[7] : bal[6];
            const u64 sB  = (rq & 2) ? s67 : s45;      // nt = 1
            const u64 w   = (g & 2) ? sB : sA;
            const u32 hlf = (mrow & 8) ? (u32)(w >> 32) : (u32)w;
            const u32 bits = (hlf >> shamt) & 0xFFu;
            i32x4 pkv;
            #pragma unroll
            for (int p = 0; p < 4; ++p) {
                const u32 tb = bits >> (2 * p);
                pkv[p] = (int)(((tb & 1u) ? 0x3C00u : 0u) |
                               ((tb & 2u) ? 0x3C000000u : 0u));
            }
            *(i32x4*)(spkbase + bufoff + wba) = pkv;
        }
        __syncthreads();

        // ---- layer 1: h1 = s0 @ (Whi + Wlo/2048) ----
        f32x4 ah[2], al[2];
        ah[0] = (f32x4){0,0,0,0}; ah[1] = (f32x4){0,0,0,0};
        al[0] = (f32x4){0,0,0,0}; al[1] = (f32x4){0,0,0,0};
        #pragma unroll
        for (int kc = 0; kc < 8; ++kc) {
            const f16x8 a = *(const f16x8*)(spkbase + bufoff + ra[kc]);
            ah[0] = MFMA16(a, whi[0][kc], ah[0]);
            al[0] = MFMA16(a, wlo[0][kc], al[0]);
            ah[1] = MFMA16(a, whi[1][kc], ah[1]);
            al[1] = MFMA16(a, wlo[1][kc], al[1]);
        }

        // ---- layer-1 state + folded output accumulation ----
        const float ctau = ctab[t];
        #pragma unroll
        for (int nt = 0; nt < 2; ++nt)
            #pragma unroll
            for (int q = 0; q < 4; ++q) {
                const int i = nt * 4 + q;
                const float h1 = ah[nt][q] + RECIP2048 * al[nt][q];
                const float m = mem1[i], s = syn1[i];
                const bool fire = m > 1.0f;       // spike from OLD mem1
                const float f = fire ? 1.0f : 0.0f;
                Zc[i]   = fmaf(ctau, f, Zc[i]);
                mem1[i] = fmaf(0.85f, m, s) - f;
                syn1[i] = fmaf(0.9f, s, h1);
            }
        bufoff ^= 8192;
    }

    // ---- out = Z @ W2 via LDS atomic reduction ----
    #pragma unroll
    for (int q = 0; q < 4; ++q) {
        const int r = g * 4 + q;
        const float z0 = Zc[q], z1 = Zc[4 + q];
        const float* w2a = W2 + (n0 + mrow) * 8;
        const float* w2b = W2 + (n0 + 16 + mrow) * 8;
        #pragma unroll
        for (int o = 0; o < 8; ++o)
            atomicAdd(&h2acc[r * 8 + o], z0 * w2a[o] + z1 * w2b[o]);
    }
    __syncthreads();
    if (tid < MROWS * 8)
        out[(size_t)row0 * 8 + tid] = h2acc[tid];
}

extern "C" void kernel_launch(void* const* d_in, const int* in_sizes, int n_in,
                              void* d_out, int out_size, void* d_ws, size_t ws_size,
                              hipStream_t stream) {
    const float* input = (const float*)d_in[0];
    const float* W0    = (const float*)d_in[1];
    const float* W1    = (const float*)d_in[2];
    const float* W2    = (const float*)d_in[3];
    float* outp = (float*)d_out;
    const int B    = in_sizes[0] / 128;
    const int grid = B / MROWS;
    snn_fused<<<grid, BLOCKSZ, 0, stream>>>(input, W0, W1, W2, outp);
}